// Round 7
// baseline (347.681 us; speedup 1.0000x reference)
//
#include <hip/hip_runtime.h>
#include <hip/hip_bf16.h>
#include <math.h>
#include <stdint.h>

typedef unsigned short u16;
typedef __attribute__((ext_vector_type(8))) short bf16x8;
typedef __attribute__((ext_vector_type(4))) float f32x4;
typedef __attribute__((ext_vector_type(16))) float f32x16;
typedef __attribute__((address_space(3))) void* as3_void;
typedef const __attribute__((address_space(1))) void* as1_cvoid;

__device__ inline u16 f2bf(float f) {
    union { float f; unsigned u; } v; v.f = f;
    unsigned r = v.u + 0x7FFFu + ((v.u >> 16) & 1u);   // round-to-nearest-even
    return (u16)(r >> 16);
}
__device__ inline float bf2f(u16 h) {
    unsigned u = ((unsigned)h) << 16;
    return __builtin_bit_cast(float, u);
}
// fast GELU (tanh form via sigmoid): x * sigma(1.5957691*(x+0.044715x^3))
__device__ inline float gelu_fast(float v) {
    float t = v * fmaf(0.07135702f, v * v, 1.5957691f);
    return v / (1.f + __expf(-t));
}

// DPP helper
template<int CTRL, int RM>
__device__ inline float dpp_mov(float v) {
    return __builtin_bit_cast(float, __builtin_amdgcn_update_dpp(
        0, __builtin_bit_cast(int, v), CTRL, RM, 0xf, false));
}
__device__ inline float wave_sum(float v) {
    v += dpp_mov<0x111, 0xf>(v);
    v += dpp_mov<0x112, 0xf>(v);
    v += dpp_mov<0x114, 0xf>(v);
    v += dpp_mov<0x118, 0xf>(v);
    v += dpp_mov<0x142, 0xa>(v);
    v += dpp_mov<0x143, 0xc>(v);
    return v;                      // lane 63 holds total
}

// ---------------------------------------------------------------------------
// Weight prep
// ---------------------------------------------------------------------------
__global__ __launch_bounds__(256)
void prep_win(const float* __restrict__ W, u16* __restrict__ Wt,
              float* __restrict__ bias, int logD, int R)
{
    int idx = blockIdx.x * 256 + threadIdx.x;
    int D = 1 << logD;
    int total = D * R;
    if (idx < total) {
        int r = idx >> logD;
        int d = idx & (D - 1);
        Wt[idx] = f2bf(W[(size_t)d * R + r]);
    }
    if (idx < R) bias[idx] = W[(size_t)D * R + idx];
}

__global__ __launch_bounds__(256)
void prep_wout(const float* __restrict__ W, u16* __restrict__ Wt, int total)
{
    int idx = blockIdx.x * 256 + threadIdx.x;
    if (idx < total) Wt[idx] = f2bf(W[idx]);
}

// ---------------------------------------------------------------------------
// k1_proj: s = x@proj (f32) + x->bf16 cast. 2 tokens per wave.
// ---------------------------------------------------------------------------
__global__ __launch_bounds__(256)
void k1_proj(const float* __restrict__ x, const float* __restrict__ proj,
             u16* __restrict__ xb, float* __restrict__ sbuf, int Ntok)
{
    __shared__ float plt[16 * 1024];
    const int tid = threadIdx.x;
    #pragma unroll
    for (int k = 0; k < 64; ++k) {
        int idx = k * 256 + tid;
        int e = idx & 15, d = idx >> 4;
        plt[e * 1024 + (d ^ (e << 2))] = proj[idx];
    }
    __syncthreads();

    const int lane = tid & 63;
    const int wid = tid >> 6;
    const int t0 = (blockIdx.x * 4 + wid) * 2;
    if (t0 >= Ntok) return;

    float s[16][2];
    #pragma unroll
    for (int e = 0; e < 16; ++e) { s[e][0] = 0.f; s[e][1] = 0.f; }

    #pragma unroll
    for (int j = 0; j < 4; ++j) {
        const int d0 = (j * 64 + lane) * 4;
        float4 xq[2];
        #pragma unroll
        for (int q = 0; q < 2; ++q) {
            xq[q] = *(const float4*)&x[(size_t)(t0 + q) * 1024 + d0];
            short4 h;
            h.x = (short)f2bf(xq[q].x); h.y = (short)f2bf(xq[q].y);
            h.z = (short)f2bf(xq[q].z); h.w = (short)f2bf(xq[q].w);
            *(short4*)&xb[(size_t)(t0 + q) * 1024 + d0] = h;
        }
        #pragma unroll
        for (int e = 0; e < 16; ++e) {
            float4 p = *(const float4*)&plt[e * 1024 + (d0 ^ (e << 2))];
            #pragma unroll
            for (int q = 0; q < 2; ++q) {
                s[e][q] = fmaf(xq[q].x, p.x, s[e][q]);
                s[e][q] = fmaf(xq[q].y, p.y, s[e][q]);
                s[e][q] = fmaf(xq[q].z, p.z, s[e][q]);
                s[e][q] = fmaf(xq[q].w, p.w, s[e][q]);
            }
        }
    }
    #pragma unroll
    for (int e = 0; e < 16; ++e) {
        s[e][0] = wave_sum(s[e][0]);
        s[e][1] = wave_sum(s[e][1]);
    }
    if (lane == 63) {
        #pragma unroll
        for (int q = 0; q < 2; ++q)
            #pragma unroll
            for (int c = 0; c < 4; ++c) {
                float4 o = { s[c * 4 + 0][q], s[c * 4 + 1][q],
                             s[c * 4 + 2][q], s[c * 4 + 3][q] };
                *(float4*)&sbuf[(size_t)(t0 + q) * 16 + c * 4] = o;
            }
    }
}

// ---------------------------------------------------------------------------
// k1_entmax: thread-per-token LN + exact 1.5-entmax
// ---------------------------------------------------------------------------
__global__ __launch_bounds__(256)
void k1_entmax(const float* __restrict__ sbuf, float* __restrict__ abuf, int Ntok)
{
    int t = blockIdx.x * 256 + threadIdx.x;
    if (t >= Ntok) return;
    float s[16];
    #pragma unroll
    for (int c = 0; c < 4; ++c) {
        float4 v = *(const float4*)&sbuf[(size_t)t * 16 + c * 4];
        s[c * 4 + 0] = v.x; s[c * 4 + 1] = v.y; s[c * 4 + 2] = v.z; s[c * 4 + 3] = v.w;
    }
    float mean = 0.f;
    #pragma unroll
    for (int e = 0; e < 16; ++e) mean += s[e];
    mean *= 0.0625f;
    float var = 0.f;
    #pragma unroll
    for (int e = 0; e < 16; ++e) { float d = s[e] - mean; var = fmaf(d, d, var); }
    var *= 0.0625f;
    float rstd = rsqrtf(var + 1e-5f);

    float z[16];
    #pragma unroll
    for (int e = 0; e < 16; ++e) z[e] = (s[e] - mean) * rstd * 0.5f;
    float zmax = z[0];
    #pragma unroll
    for (int e = 1; e < 16; ++e) zmax = fmaxf(zmax, z[e]);
    #pragma unroll
    for (int e = 0; e < 16; ++e) z[e] -= zmax;

    float zs[16];
    #pragma unroll
    for (int e = 0; e < 16; ++e) zs[e] = z[e];
    #pragma unroll
    for (int k = 2; k <= 16; k <<= 1) {
        #pragma unroll
        for (int j = k >> 1; j > 0; j >>= 1) {
            #pragma unroll
            for (int i = 0; i < 16; ++i) {
                int l = i ^ j;
                if (l > i) {
                    float a = zs[i], b = zs[l];
                    bool asc = ((i & k) == 0);
                    bool sw = asc ? (a > b) : (a < b);
                    if (sw) { zs[i] = b; zs[l] = a; }
                }
            }
        }
    }
    float csum = 0.f, csq = 0.f, tau_star = -3.4e38f;
    #pragma unroll
    for (int kk = 1; kk <= 16; ++kk) {
        float v = zs[16 - kk];
        csum += v; csq += v * v;
        float kf = (float)kk;
        float mn = csum / kf;
        float ms = csq / kf;
        float ss = kf * (ms - mn * mn);
        float delta = fmaxf((1.f - ss) / kf, 0.f);
        float tau = mn - sqrtf(delta);
        if (tau <= v) tau_star = tau;
    }
    #pragma unroll
    for (int c = 0; c < 4; ++c) {
        float4 o;
        float p0 = fmaxf(z[c * 4 + 0] - tau_star, 0.f);
        float p1 = fmaxf(z[c * 4 + 1] - tau_star, 0.f);
        float p2 = fmaxf(z[c * 4 + 2] - tau_star, 0.f);
        float p3 = fmaxf(z[c * 4 + 3] - tau_star, 0.f);
        o.x = p0 * p0; o.y = p1 * p1; o.z = p2 * p2; o.w = p3 * p3;
        *(float4*)&abuf[(size_t)t * 16 + c * 4] = o;
    }
}

// ---------------------------------------------------------------------------
// gcompute: g1 = a@C1, g2 = a@C2 -> bf16. One wave per token.
// ---------------------------------------------------------------------------
__global__ __launch_bounds__(256)
void gcompute(const float* __restrict__ abuf, const float* __restrict__ C1,
              const float* __restrict__ C2, u16* __restrict__ g1,
              u16* __restrict__ g2, int Ntok)
{
    const int tid = threadIdx.x;
    const int lane = tid & 63;
    const int t = blockIdx.x * 4 + (tid >> 6);
    if (t >= Ntok) return;
    float a[16];
    #pragma unroll
    for (int c = 0; c < 4; ++c) {
        float4 v = *(const float4*)&abuf[(size_t)t * 16 + c * 4];
        a[c * 4 + 0] = v.x; a[c * 4 + 1] = v.y; a[c * 4 + 2] = v.z; a[c * 4 + 3] = v.w;
    }
    #pragma unroll
    for (int c8 = 0; c8 < 8; ++c8) {
        int col = c8 * 64 + lane;
        float t1 = 0.f, t2 = 0.f;
        #pragma unroll
        for (int e = 0; e < 16; ++e) {
            t1 = fmaf(a[e], C1[e * 512 + col], t1);
            t2 = fmaf(a[e], C2[e * 512 + col], t2);
        }
        g1[(size_t)t * 512 + col] = f2bf(t1);
        g2[(size_t)t * 512 + col] = f2bf(t2);
    }
}

// ---------------------------------------------------------------------------
// gemm_bt: m97 single-buffer structure with 32x32x16 MFMA (half the MFMA and
// ds_read instruction count of 16x16x32 at same FLOPs). 128x128 tile, 4
// waves, BK=64, 32 KB LDS, zero-conflict XOR swizzle, hoisted staging
// pointers. C/D layout (m74/m101-verified): col=lane&31,
// row=(reg&3)+8*(reg>>2)+4*(lane>>5).
// MODE 0: fast-gelu->bf16; MODE 1: (acc+bias)*g ->bf16 (g bf16, may alias
// Cout); MODE 2: ->f32.
// ---------------------------------------------------------------------------
template<int MODE>
__global__ __launch_bounds__(256, 4)
void gemm_bt(const u16* __restrict__ A, const u16* __restrict__ Bt,
             const float* __restrict__ bias, const u16* __restrict__ gmat,
             void* __restrict__ Cout, int M, int Nn, int K, int tilesN)
{
    __shared__ __align__(1024) char smem[32768];   // A 16KB + B 16KB
    const int tid = threadIdx.x;
    const int lane = tid & 63;
    const int wid = tid >> 6;

    int bid = blockIdx.x;
    {
        int nwg = gridDim.x;
        if (nwg >= 16) {
            int q = nwg >> 3, r = nwg & 7;
            int xcd = bid & 7, loc = bid >> 3;
            bid = (xcd < r ? xcd * (q + 1) : r * (q + 1) + (xcd - r) * q) + loc;
        }
    }
    const int m0 = (bid / tilesN) * 128;
    const int n0 = (bid % tilesN) * 128;
    const int wm = (wid >> 1) * 64;
    const int wn = (wid & 1) * 64;

    f32x16 acc[2][2];
    #pragma unroll
    for (int i = 0; i < 2; ++i)
        #pragma unroll
        for (int j = 0; j < 2; ++j)
            #pragma unroll
            for (int r = 0; r < 16; ++r) acc[i][j][r] = 0.f;

    // hoisted per-lane staging pointers (advance by 64 elems per K-step)
    const u16* gaP[4];
    const u16* gbP[4];
    #pragma unroll
    for (int i = 0; i < 4; ++i) {
        int q = (wid * 4 + i) * 64 + lane;
        int row = q >> 3;
        int c = (q & 7) ^ (row & 7);           // pre-swizzled source chunk
        gaP[i] = A + (size_t)(m0 + row) * K + c * 8;
        gbP[i] = Bt + (size_t)(n0 + row) * K + c * 8;
    }

    const int r5 = lane & 31;
    const int hi5 = lane >> 5;
    const int arow0 = wm + r5;
    const int brow0 = wn + r5;

    const int nsteps = K >> 6;
    for (int ks = 0; ks < nsteps; ++ks) {
        #pragma unroll
        for (int i = 0; i < 4; ++i) {
            __builtin_amdgcn_global_load_lds((as1_cvoid)gaP[i],
                (as3_void)&smem[(wid * 4 + i) * 1024], 16, 0, 0);
            gaP[i] += 64;
        }
        #pragma unroll
        for (int i = 0; i < 4; ++i) {
            __builtin_amdgcn_global_load_lds((as1_cvoid)gbP[i],
                (as3_void)&smem[16384 + (wid * 4 + i) * 1024], 16, 0, 0);
            gbP[i] += 64;
        }
        __syncthreads();
        #pragma unroll
        for (int ksl = 0; ksl < 4; ++ksl) {
            bf16x8 aR[2], bR[2];
            #pragma unroll
            for (int i2 = 0; i2 < 2; ++i2) {
                int rowa = arow0 + i2 * 32;
                aR[i2] = *(const bf16x8*)
                    &smem[rowa * 128 + ((((ksl << 1) | hi5) ^ (rowa & 7)) << 4)];
                int rowb = brow0 + i2 * 32;
                bR[i2] = *(const bf16x8*)
                    &smem[16384 + rowb * 128 + ((((ksl << 1) | hi5) ^ (rowb & 7)) << 4)];
            }
            #pragma unroll
            for (int i2 = 0; i2 < 2; ++i2)
                #pragma unroll
                for (int j2 = 0; j2 < 2; ++j2)
                    acc[i2][j2] = __builtin_amdgcn_mfma_f32_32x32x16_bf16(
                        aR[i2], bR[j2], acc[i2][j2], 0, 0, 0);
        }
        __syncthreads();
    }

    // epilogue: 32x32 C/D layout: col=lane&31, row=(reg&3)+8*(reg>>2)+4*hi5
    const int rbase = hi5 * 4;
    #pragma unroll
    for (int i2 = 0; i2 < 2; ++i2) {
        #pragma unroll
        for (int j2 = 0; j2 < 2; ++j2) {
            int col = n0 + wn + j2 * 32 + r5;
            float bv = (MODE == 1) ? bias[col] : 0.f;
            #pragma unroll
            for (int reg = 0; reg < 16; ++reg) {
                int row = m0 + wm + i2 * 32 + (reg & 3) + 8 * (reg >> 2) + rbase;
                float v = acc[i2][j2][reg];
                if (MODE == 0) {
                    ((u16*)Cout)[(size_t)row * Nn + col] = f2bf(gelu_fast(v));
                } else if (MODE == 1) {
                    v = (v + bv) * bf2f(gmat[(size_t)row * Nn + col]);
                    ((u16*)Cout)[(size_t)row * Nn + col] = f2bf(v);
                } else {
                    ((float*)Cout)[(size_t)row * Nn + col] = v;
                }
            }
        }
    }
}

// ---------------------------------------------------------------------------
extern "C" void kernel_launch(void* const* d_in, const int* in_sizes, int n_in,
                              void* d_out, int out_size, void* d_ws, size_t ws_size,
                              hipStream_t stream)
{
    const float* x     = (const float*)d_in[0];
    const float* proj  = (const float*)d_in[1];
    const float* C1    = (const float*)d_in[2];
    const float* Win1  = (const float*)d_in[3];
    const float* Wout1 = (const float*)d_in[4];
    const float* C2    = (const float*)d_in[5];
    const float* Win2  = (const float*)d_in[6];
    const float* Wout2 = (const float*)d_in[7];

    const int D = 1024, O = 4096, R = 512, D2 = 1024;
    const int Ntok = in_sizes[0] / D;   // 16384

    char* ws = (char*)d_ws;
    size_t off = 0;
    auto alloc = [&](size_t bytes) -> void* {
        void* p = ws + off;
        off += (bytes + 255) & ~(size_t)255;
        return p;
    };
    // ---- persistent ----
    u16*   z1  = (u16*)  alloc((size_t)Ntok * R * 2);    // aliases g1
    u16*   z2  = (u16*)  alloc((size_t)Ntok * R * 2);    // aliases g2
    u16*   w1o = (u16*)  alloc((size_t)O * R * 2);       // Wout1  [4096,512]
    u16*   w2t = (u16*)  alloc((size_t)R * O * 2);       // Win2^T [512,4096]
    u16*   w2o = (u16*)  alloc((size_t)D2 * R * 2);      // Wout2  [1024,512]
    float* b1  = (float*)alloc(R * 4);
    float* b2  = (float*)alloc(R * 4);
    size_t persist_end = off;

    // ---- transient (dead before first G2) ----
    u16*   xb   = (u16*)  alloc((size_t)Ntok * D * 2);
    u16*   w1t  = (u16*)  alloc((size_t)R * D * 2);      // Win1^T [512,1024]
    float* sbuf = (float*)alloc((size_t)Ntok * 16 * 4);
    float* abuf = (float*)alloc((size_t)Ntok * 16 * 4);

    // hbuf overlays the transient region
    size_t hAvail = (ws_size > persist_end) ? (ws_size - persist_end) : 0;
    long long chRows = (long long)(hAvail / ((size_t)O * 2));
    chRows &= ~127LL;
    int CH = (chRows > Ntok) ? Ntok : (int)chRows;
    if (CH < 128) CH = 128;
    u16* hbuf = (u16*)(ws + persist_end);

    u16* g1 = z1;
    u16* g2 = z2;

    // weight prep
    prep_win <<<(D * R + 255) / 256, 256, 0, stream>>>(Win1, w1t, b1, 10, R);
    prep_win <<<(O * R + 255) / 256, 256, 0, stream>>>(Win2, w2t, b2, 12, R);
    prep_wout<<<(O * R + 255) / 256, 256, 0, stream>>>(Wout1, w1o, O * R);
    prep_wout<<<(D2 * R + 255) / 256, 256, 0, stream>>>(Wout2, w2o, D2 * R);

    // gating path
    k1_proj  <<<Ntok / 8, 256, 0, stream>>>(x, proj, xb, sbuf, Ntok);
    k1_entmax<<<(Ntok + 255) / 256, 256, 0, stream>>>(sbuf, abuf, Ntok);
    gcompute <<<(Ntok + 3) / 4, 256, 0, stream>>>(abuf, C1, C2, g1, g2, Ntok);

    // G1: z1 = (x @ Win1 + b1) * g1   [N,512], K=1024  (in-place over g1)
    gemm_bt<1><<<(Ntok / 128) * (R / 128), 256, 0, stream>>>(
        xb, w1t, b1, g1, z1, Ntok, R, D, R / 128);

    // chunked: G2: h = gelu(z1 @ Wout1^T) [N,4096], K=512
    //          G3: z2 = (h @ Win2 + b2) * g2 [N,512], K=4096 (in-place)
    for (int r0 = 0; r0 < Ntok; r0 += CH) {
        int cm = Ntok - r0; if (cm > CH) cm = CH;
        gemm_bt<0><<<(cm / 128) * (O / 128), 256, 0, stream>>>(
            z1 + (size_t)r0 * R, w1o, nullptr, nullptr,
            hbuf, cm, O, R, O / 128);
        gemm_bt<1><<<(cm / 128) * (R / 128), 256, 0, stream>>>(
            hbuf, w2t, b2, g2 + (size_t)r0 * R,
            z2 + (size_t)r0 * R, cm, R, O, R / 128);
    }

    // G4: out = z2 @ Wout2^T  [N,1024] f32, K=512
    gemm_bt<2><<<(Ntok / 128) * (D2 / 128), 256, 0, stream>>>(
        z2, w2o, nullptr, nullptr, d_out, Ntok, D2, R, D2 / 128);
}

// Round 8
// 324.348 us; speedup vs baseline: 1.0719x; 1.0719x over previous
//
#include <hip/hip_runtime.h>
#include <hip/hip_bf16.h>
#include <math.h>
#include <stdint.h>

typedef unsigned short u16;
typedef __attribute__((ext_vector_type(8))) short bf16x8;
typedef __attribute__((ext_vector_type(4))) float f32x4;
typedef __attribute__((address_space(3))) void* as3_void;
typedef const __attribute__((address_space(1))) void* as1_cvoid;

__device__ inline u16 f2bf(float f) {
    union { float f; unsigned u; } v; v.f = f;
    unsigned r = v.u + 0x7FFFu + ((v.u >> 16) & 1u);   // round-to-nearest-even
    return (u16)(r >> 16);
}
__device__ inline float bf2f(u16 h) {
    unsigned u = ((unsigned)h) << 16;
    return __builtin_bit_cast(float, u);
}
// fast GELU (tanh form via sigmoid): x * sigma(1.5957691*(x+0.044715x^3))
__device__ inline float gelu_fast(float v) {
    float t = v * fmaf(0.07135702f, v * v, 1.5957691f);
    return v / (1.f + __expf(-t));
}

// DPP helper
template<int CTRL, int RM>
__device__ inline float dpp_mov(float v) {
    return __builtin_bit_cast(float, __builtin_amdgcn_update_dpp(
        0, __builtin_bit_cast(int, v), CTRL, RM, 0xf, false));
}
__device__ inline float wave_sum(float v) {
    v += dpp_mov<0x111, 0xf>(v);
    v += dpp_mov<0x112, 0xf>(v);
    v += dpp_mov<0x114, 0xf>(v);
    v += dpp_mov<0x118, 0xf>(v);
    v += dpp_mov<0x142, 0xa>(v);
    v += dpp_mov<0x143, 0xc>(v);
    return v;                      // lane 63 holds total
}

// ---------------------------------------------------------------------------
// prep_all: all weight prep in ONE kernel (transposes + bf16 casts + biases)
// ---------------------------------------------------------------------------
__global__ __launch_bounds__(256)
void prep_all(const float* __restrict__ Win1, const float* __restrict__ Wout1,
              const float* __restrict__ Win2, const float* __restrict__ Wout2,
              u16* __restrict__ w1t, u16* __restrict__ w1o,
              u16* __restrict__ w2t, u16* __restrict__ w2o,
              float* __restrict__ b1, float* __restrict__ b2)
{
    int idx = blockIdx.x * 256 + threadIdx.x;
    if (idx < 524288) {            // w1t[r][d] = Win1[d][r], D=1024 R=512
        int r = idx >> 10, d = idx & 1023;
        w1t[idx] = f2bf(Win1[(size_t)d * 512 + r]);
    }
    if (idx < 2097152) {           // w1o = bf16(Wout1), [4096,512]
        w1o[idx] = f2bf(Wout1[idx]);
    }
    if (idx < 2097152) {           // w2t[r][o] = Win2[o][r], O=4096 R=512
        int r = idx >> 12, o = idx & 4095;
        w2t[idx] = f2bf(Win2[(size_t)o * 512 + r]);
    }
    if (idx < 524288) {            // w2o = bf16(Wout2), [1024,512]
        w2o[idx] = f2bf(Wout2[idx]);
    }
    if (idx < 512) {
        b1[idx] = Win1[(size_t)1024 * 512 + idx];
        b2[idx] = Win2[(size_t)4096 * 512 + idx];
    }
}

// ---------------------------------------------------------------------------
// k1_proj: s = x@proj (f32) + x->bf16 cast. 2 tokens per wave.
// ---------------------------------------------------------------------------
__global__ __launch_bounds__(256)
void k1_proj(const float* __restrict__ x, const float* __restrict__ proj,
             u16* __restrict__ xb, float* __restrict__ sbuf, int Ntok)
{
    __shared__ float plt[16 * 1024];
    const int tid = threadIdx.x;
    #pragma unroll
    for (int k = 0; k < 64; ++k) {
        int idx = k * 256 + tid;
        int e = idx & 15, d = idx >> 4;
        plt[e * 1024 + (d ^ (e << 2))] = proj[idx];
    }
    __syncthreads();

    const int lane = tid & 63;
    const int wid = tid >> 6;
    const int t0 = (blockIdx.x * 4 + wid) * 2;
    if (t0 >= Ntok) return;

    float s[16][2];
    #pragma unroll
    for (int e = 0; e < 16; ++e) { s[e][0] = 0.f; s[e][1] = 0.f; }

    #pragma unroll
    for (int j = 0; j < 4; ++j) {
        const int d0 = (j * 64 + lane) * 4;
        float4 xq[2];
        #pragma unroll
        for (int q = 0; q < 2; ++q) {
            xq[q] = *(const float4*)&x[(size_t)(t0 + q) * 1024 + d0];
            short4 h;
            h.x = (short)f2bf(xq[q].x); h.y = (short)f2bf(xq[q].y);
            h.z = (short)f2bf(xq[q].z); h.w = (short)f2bf(xq[q].w);
            *(short4*)&xb[(size_t)(t0 + q) * 1024 + d0] = h;
        }
        #pragma unroll
        for (int e = 0; e < 16; ++e) {
            float4 p = *(const float4*)&plt[e * 1024 + (d0 ^ (e << 2))];
            #pragma unroll
            for (int q = 0; q < 2; ++q) {
                s[e][q] = fmaf(xq[q].x, p.x, s[e][q]);
                s[e][q] = fmaf(xq[q].y, p.y, s[e][q]);
                s[e][q] = fmaf(xq[q].z, p.z, s[e][q]);
                s[e][q] = fmaf(xq[q].w, p.w, s[e][q]);
            }
        }
    }
    #pragma unroll
    for (int e = 0; e < 16; ++e) {
        s[e][0] = wave_sum(s[e][0]);
        s[e][1] = wave_sum(s[e][1]);
    }
    if (lane == 63) {
        #pragma unroll
        for (int q = 0; q < 2; ++q)
            #pragma unroll
            for (int c = 0; c < 4; ++c) {
                float4 o = { s[c * 4 + 0][q], s[c * 4 + 1][q],
                             s[c * 4 + 2][q], s[c * 4 + 3][q] };
                *(float4*)&sbuf[(size_t)(t0 + q) * 16 + c * 4] = o;
            }
    }
}

// ---------------------------------------------------------------------------
// k1_entmax: thread-per-token LN + exact 1.5-entmax
// ---------------------------------------------------------------------------
__global__ __launch_bounds__(256)
void k1_entmax(const float* __restrict__ sbuf, float* __restrict__ abuf, int Ntok)
{
    int t = blockIdx.x * 256 + threadIdx.x;
    if (t >= Ntok) return;
    float s[16];
    #pragma unroll
    for (int c = 0; c < 4; ++c) {
        float4 v = *(const float4*)&sbuf[(size_t)t * 16 + c * 4];
        s[c * 4 + 0] = v.x; s[c * 4 + 1] = v.y; s[c * 4 + 2] = v.z; s[c * 4 + 3] = v.w;
    }
    float mean = 0.f;
    #pragma unroll
    for (int e = 0; e < 16; ++e) mean += s[e];
    mean *= 0.0625f;
    float var = 0.f;
    #pragma unroll
    for (int e = 0; e < 16; ++e) { float d = s[e] - mean; var = fmaf(d, d, var); }
    var *= 0.0625f;
    float rstd = rsqrtf(var + 1e-5f);

    float z[16];
    #pragma unroll
    for (int e = 0; e < 16; ++e) z[e] = (s[e] - mean) * rstd * 0.5f;
    float zmax = z[0];
    #pragma unroll
    for (int e = 1; e < 16; ++e) zmax = fmaxf(zmax, z[e]);
    #pragma unroll
    for (int e = 0; e < 16; ++e) z[e] -= zmax;

    float zs[16];
    #pragma unroll
    for (int e = 0; e < 16; ++e) zs[e] = z[e];
    #pragma unroll
    for (int k = 2; k <= 16; k <<= 1) {
        #pragma unroll
        for (int j = k >> 1; j > 0; j >>= 1) {
            #pragma unroll
            for (int i = 0; i < 16; ++i) {
                int l = i ^ j;
                if (l > i) {
                    float a = zs[i], b = zs[l];
                    bool asc = ((i & k) == 0);
                    bool sw = asc ? (a > b) : (a < b);
                    if (sw) { zs[i] = b; zs[l] = a; }
                }
            }
        }
    }
    float csum = 0.f, csq = 0.f, tau_star = -3.4e38f;
    #pragma unroll
    for (int kk = 1; kk <= 16; ++kk) {
        float v = zs[16 - kk];
        csum += v; csq += v * v;
        float kf = (float)kk;
        float mn = csum / kf;
        float ms = csq / kf;
        float ss = kf * (ms - mn * mn);
        float delta = fmaxf((1.f - ss) / kf, 0.f);
        float tau = mn - sqrtf(delta);
        if (tau <= v) tau_star = tau;
    }
    #pragma unroll
    for (int c = 0; c < 4; ++c) {
        float4 o;
        float p0 = fmaxf(z[c * 4 + 0] - tau_star, 0.f);
        float p1 = fmaxf(z[c * 4 + 1] - tau_star, 0.f);
        float p2 = fmaxf(z[c * 4 + 2] - tau_star, 0.f);
        float p3 = fmaxf(z[c * 4 + 3] - tau_star, 0.f);
        o.x = p0 * p0; o.y = p1 * p1; o.z = p2 * p2; o.w = p3 * p3;
        *(float4*)&abuf[(size_t)t * 16 + c * 4] = o;
    }
}

// ---------------------------------------------------------------------------
// gcompute: g1 = a@C1, g2 = a@C2 -> bf16. One wave per token.
// ---------------------------------------------------------------------------
__global__ __launch_bounds__(256)
void gcompute(const float* __restrict__ abuf, const float* __restrict__ C1,
              const float* __restrict__ C2, u16* __restrict__ g1,
              u16* __restrict__ g2, int Ntok)
{
    const int tid = threadIdx.x;
    const int lane = tid & 63;
    const int t = blockIdx.x * 4 + (tid >> 6);
    if (t >= Ntok) return;
    float a[16];
    #pragma unroll
    for (int c = 0; c < 4; ++c) {
        float4 v = *(const float4*)&abuf[(size_t)t * 16 + c * 4];
        a[c * 4 + 0] = v.x; a[c * 4 + 1] = v.y; a[c * 4 + 2] = v.z; a[c * 4 + 3] = v.w;
    }
    #pragma unroll
    for (int c8 = 0; c8 < 8; ++c8) {
        int col = c8 * 64 + lane;
        float t1 = 0.f, t2 = 0.f;
        #pragma unroll
        for (int e = 0; e < 16; ++e) {
            t1 = fmaf(a[e], C1[e * 512 + col], t1);
            t2 = fmaf(a[e], C2[e * 512 + col], t2);
        }
        g1[(size_t)t * 512 + col] = f2bf(t1);
        g2[(size_t)t * 512 + col] = f2bf(t2);
    }
}

// ---------------------------------------------------------------------------
// gemm_bt: m97 single-buffer structure (R5-proven: 695+ TF, 0 conflicts).
// 128x128 tile, 4 waves, BK=64, 32 KB LDS, 16x16x32 MFMA, XOR swizzle.
// NEW: M-panel-per-XCD block mapping — xcd=bid&7 owns a contiguous M-panel,
// loc iterates N-fastest inside it: A-tiles fetched once per XCD, B-panel
// (<=4MB) stays L2-resident per XCD. Requires (Mtiles%8)==0 (else linear).
// MODE 0: fast-gelu->bf16; MODE 1: (acc+bias)*g ->bf16 (g bf16, may alias
// Cout); MODE 2: ->f32.
// ---------------------------------------------------------------------------
template<int MODE>
__global__ __launch_bounds__(256, 4)
void gemm_bt(const u16* __restrict__ A, const u16* __restrict__ Bt,
             const float* __restrict__ bias, const u16* __restrict__ gmat,
             void* __restrict__ Cout, int M, int Nn, int K, int tilesN)
{
    __shared__ __align__(1024) char smem[32768];   // A 16KB + B 16KB
    const int tid = threadIdx.x;
    const int lane = tid & 63;
    const int wid = tid >> 6;

    // M-panel-per-XCD mapping
    int m_t, n_t;
    {
        int bid = blockIdx.x;
        int Mtiles = gridDim.x / tilesN;
        if ((Mtiles & 7) == 0) {
            int xcd = bid & 7, loc = bid >> 3;
            int lm = loc / tilesN;
            m_t = xcd * (Mtiles >> 3) + lm;
            n_t = loc - lm * tilesN;
        } else {
            m_t = bid / tilesN;
            n_t = bid % tilesN;
        }
    }
    const int m0 = m_t * 128;
    const int n0 = n_t * 128;
    const int wm = (wid >> 1) * 64;
    const int wn = (wid & 1) * 64;

    f32x4 acc[4][4];
    #pragma unroll
    for (int i = 0; i < 4; ++i)
        #pragma unroll
        for (int j = 0; j < 4; ++j) acc[i][j] = (f32x4){0.f, 0.f, 0.f, 0.f};

    const int nsteps = K >> 6;
    for (int ks = 0; ks < nsteps; ++ks) {
        const int k0 = ks << 6;
        // stage A/B tiles [128][64]; linear LDS dest, source chunk XOR-swizzled
        #pragma unroll
        for (int i = 0; i < 4; ++i) {
            int q = (wid * 4 + i) * 64 + lane;
            int row = q >> 3;
            int c = (q & 7) ^ (row & 7);
            __builtin_amdgcn_global_load_lds(
                (as1_cvoid)(A + (size_t)(m0 + row) * K + k0 + c * 8),
                (as3_void)&smem[(wid * 4 + i) * 1024], 16, 0, 0);
        }
        #pragma unroll
        for (int i = 0; i < 4; ++i) {
            int q = (wid * 4 + i) * 64 + lane;
            int row = q >> 3;
            int c = (q & 7) ^ (row & 7);
            __builtin_amdgcn_global_load_lds(
                (as1_cvoid)(Bt + (size_t)(n0 + row) * K + k0 + c * 8),
                (as3_void)&smem[16384 + (wid * 4 + i) * 1024], 16, 0, 0);
        }
        __syncthreads();
        #pragma unroll
        for (int kk = 0; kk < 2; ++kk) {
            bf16x8 af[4], bfr[4];
            const int slot = kk * 4 + (lane >> 4);
            #pragma unroll
            for (int i = 0; i < 4; ++i) {
                int row = wm + i * 16 + (lane & 15);
                af[i] = *(const bf16x8*)
                    &smem[row * 128 + ((slot ^ (row & 7)) << 4)];
            }
            #pragma unroll
            for (int j = 0; j < 4; ++j) {
                int row = wn + j * 16 + (lane & 15);
                bfr[j] = *(const bf16x8*)
                    &smem[16384 + row * 128 + ((slot ^ (row & 7)) << 4)];
            }
            #pragma unroll
            for (int i = 0; i < 4; ++i)
                #pragma unroll
                for (int j = 0; j < 4; ++j)
                    acc[i][j] = __builtin_amdgcn_mfma_f32_16x16x32_bf16(
                        af[i], bfr[j], acc[i][j], 0, 0, 0);
        }
        __syncthreads();
    }

    const int cl = lane & 15;
    const int rq = (lane >> 4) * 4;
    #pragma unroll
    for (int i = 0; i < 4; ++i) {
        #pragma unroll
        for (int j = 0; j < 4; ++j) {
            int col = n0 + wn + j * 16 + cl;
            float bv = (MODE == 1) ? bias[col] : 0.f;
            #pragma unroll
            for (int r = 0; r < 4; ++r) {
                int row = m0 + wm + i * 16 + rq + r;
                float v = acc[i][j][r];
                if (MODE == 0) {
                    ((u16*)Cout)[(size_t)row * Nn + col] = f2bf(gelu_fast(v));
                } else if (MODE == 1) {
                    v = (v + bv) * bf2f(gmat[(size_t)row * Nn + col]);
                    ((u16*)Cout)[(size_t)row * Nn + col] = f2bf(v);
                } else {
                    ((float*)Cout)[(size_t)row * Nn + col] = v;
                }
            }
        }
    }
}

// ---------------------------------------------------------------------------
extern "C" void kernel_launch(void* const* d_in, const int* in_sizes, int n_in,
                              void* d_out, int out_size, void* d_ws, size_t ws_size,
                              hipStream_t stream)
{
    const float* x     = (const float*)d_in[0];
    const float* proj  = (const float*)d_in[1];
    const float* C1    = (const float*)d_in[2];
    const float* Win1  = (const float*)d_in[3];
    const float* Wout1 = (const float*)d_in[4];
    const float* C2    = (const float*)d_in[5];
    const float* Win2  = (const float*)d_in[6];
    const float* Wout2 = (const float*)d_in[7];

    const int D = 1024, O = 4096, R = 512, D2 = 1024;
    const int Ntok = in_sizes[0] / D;   // 16384

    char* ws = (char*)d_ws;
    size_t off = 0;
    auto alloc = [&](size_t bytes) -> void* {
        void* p = ws + off;
        off += (bytes + 255) & ~(size_t)255;
        return p;
    };
    // ---- persistent ----
    u16*   z1  = (u16*)  alloc((size_t)Ntok * R * 2);    // aliases g1
    u16*   z2  = (u16*)  alloc((size_t)Ntok * R * 2);    // aliases g2
    u16*   w1o = (u16*)  alloc((size_t)O * R * 2);       // Wout1  [4096,512]
    u16*   w2t = (u16*)  alloc((size_t)R * O * 2);       // Win2^T [512,4096]
    u16*   w2o = (u16*)  alloc((size_t)D2 * R * 2);      // Wout2  [1024,512]
    float* b1  = (float*)alloc(R * 4);
    float* b2  = (float*)alloc(R * 4);
    size_t persist_end = off;

    // ---- transient (dead before first G2) ----
    u16*   xb   = (u16*)  alloc((size_t)Ntok * D * 2);
    u16*   w1t  = (u16*)  alloc((size_t)R * D * 2);      // Win1^T [512,1024]
    float* sbuf = (float*)alloc((size_t)Ntok * 16 * 4);
    float* abuf = (float*)alloc((size_t)Ntok * 16 * 4);

    // hbuf overlays the transient region; chunk rows multiple of 1024 so the
    // per-chunk Mtiles stays divisible by 8 (M-panel XCD mapping)
    size_t hAvail = (ws_size > persist_end) ? (ws_size - persist_end) : 0;
    long long chRows = (long long)(hAvail / ((size_t)O * 2));
    chRows &= ~1023LL;
    int CH = (chRows > Ntok) ? Ntok : (int)chRows;
    if (CH < 1024) CH = 1024;
    u16* hbuf = (u16*)(ws + persist_end);

    u16* g1 = z1;
    u16* g2 = z2;

    // fused weight prep (one launch)
    prep_all<<<(O * R + 255) / 256, 256, 0, stream>>>(
        Win1, Wout1, Win2, Wout2, w1t, w1o, w2t, w2o, b1, b2);

    // gating path
    k1_proj  <<<Ntok / 8, 256, 0, stream>>>(x, proj, xb, sbuf, Ntok);
    k1_entmax<<<(Ntok + 255) / 256, 256, 0, stream>>>(sbuf, abuf, Ntok);
    gcompute <<<(Ntok + 3) / 4, 256, 0, stream>>>(abuf, C1, C2, g1, g2, Ntok);

    // G1: z1 = (x @ Win1 + b1) * g1   [N,512], K=1024  (in-place over g1)
    gemm_bt<1><<<(Ntok / 128) * (R / 128), 256, 0, stream>>>(
        xb, w1t, b1, g1, z1, Ntok, R, D, R / 128);

    // chunked: G2: h = gelu(z1 @ Wout1^T) [N,4096], K=512
    //          G3: z2 = (h @ Win2 + b2) * g2 [N,512], K=4096 (in-place)
    for (int r0 = 0; r0 < Ntok; r0 += CH) {
        int cm = Ntok - r0; if (cm > CH) cm = CH;
        gemm_bt<0><<<(cm / 128) * (O / 128), 256, 0, stream>>>(
            z1 + (size_t)r0 * R, w1o, nullptr, nullptr,
            hbuf, cm, O, R, O / 128);
        gemm_bt<1><<<(cm / 128) * (R / 128), 256, 0, stream>>>(
            hbuf, w2t, b2, g2 + (size_t)r0 * R,
            z2 + (size_t)r0 * R, cm, R, O, R / 128);
    }

    // G4: out = z2 @ Wout2^T  [N,1024] f32, K=512
    gemm_bt<2><<<(Ntok / 128) * (D2 / 128), 256, 0, stream>>>(
        z2, w2o, nullptr, nullptr, d_out, Ntok, D2, R, D2 / 128);
}